// Round 10
// baseline (660.905 us; speedup 1.0000x reference)
//
#include <hip/hip_runtime.h>
#include <stdint.h>

#define N_NODES 20000
#define N_EDGES 320000
#define N_BATCH 32
#define DIM     128

typedef _Float16 v8h __attribute__((ext_vector_type(8)));
typedef float v4f __attribute__((ext_vector_type(4)));

static inline int cdiv(int a, int b){ return (a + b - 1) / b; }

// pack two f32 -> two f16 (RTZ), single v_cvt_pkrtz_f16_f32 (GCN-era instr)
__device__ __forceinline__ uint32_t pk_f16(float lo, float hi){
  auto h = __builtin_amdgcn_cvt_pkrtz(lo, hi);   // __fp16 ext_vector(2)
  return __builtin_bit_cast(uint32_t, h);
}
// acc += f32(f16 from lo/hi half of u) * w  -- single v_fma_mix_f32 (gfx906+)
__device__ __forceinline__ void fmix_lo(float& acc, uint32_t u, float w){
  asm("v_fma_mix_f32 %0, %1, %2, %0 op_sel:[0,0,0] op_sel_hi:[1,0,0]"
      : "+v"(acc) : "v"(u), "v"(w));
}
__device__ __forceinline__ void fmix_hi(float& acc, uint32_t u, float w){
  asm("v_fma_mix_f32 %0, %1, %2, %0 op_sel:[1,0,0] op_sel_hi:[1,0,0]"
      : "+v"(acc) : "v"(u), "v"(w));
}

// ---------------- setup kernels ----------------

__global__ void k_zero(uint32_t* p, int n){
  int i = blockIdx.x * 256 + threadIdx.x;
  if (i < n) p[i] = 0u;
}

__global__ void k_hist(const int* __restrict__ ei, uint32_t* __restrict__ hist){
  int e = blockIdx.x * 256 + threadIdx.x;
  if (e < N_EDGES){
    int d = ei[N_EDGES + e];
    atomicAdd(&hist[d], 1u);
  }
}

// single-block exclusive scan of hist -> row_start; also deg-derived dinv, c-init
__global__ void k_scan(const uint32_t* __restrict__ hist, uint32_t* __restrict__ row_start,
                       float* __restrict__ dinv, float* __restrict__ cw){
  __shared__ uint32_t part[1024];
  const int t = threadIdx.x;
  const int base = t * 20;                       // 1024*20 = 20480 >= 20000
  uint32_t cnt[20];
  uint32_t s = 0;
  #pragma unroll
  for (int i = 0; i < 20; i++){
    int idx = base + i;
    uint32_t v = (idx < N_NODES) ? hist[idx] : 0u;
    cnt[i] = v; s += v;
  }
  part[t] = s;
  __syncthreads();
  for (int off = 1; off < 1024; off <<= 1){      // inclusive Hillis-Steele
    uint32_t v = part[t];
    uint32_t add = (t >= off) ? part[t - off] : 0u;
    __syncthreads();
    part[t] = v + add;
    __syncthreads();
  }
  uint32_t run = (t > 0) ? part[t - 1] : 0u;     // exclusive prefix
  #pragma unroll
  for (int i = 0; i < 20; i++){
    int idx = base + i;
    if (idx < N_NODES){
      row_start[idx] = run;
      float deg = (float)cnt[i] + 1.0f;
      dinv[idx] = rsqrtf(deg);
      cw[idx]   = 1.0f / deg;                    // self_norm; edge terms added by k_edge
      run += cnt[i];
    }
  }
}

// emeta.x = src * 256 (byte offset of src row in a batch slab), emeta.y = f32 weight bits
__global__ void k_edge(const int* __restrict__ ei, const uint32_t* __restrict__ row_start,
                       uint32_t* __restrict__ cursor, const float* __restrict__ dinv,
                       float* __restrict__ cw, int2* __restrict__ emeta){
  int e = blockIdx.x * 256 + threadIdx.x;
  if (e >= N_EDGES) return;
  int s = ei[e];
  int d = ei[N_EDGES + e];
  float w = dinv[s] * dinv[d];
  atomicAdd(&cw[s], w);
  uint32_t off = atomicAdd(&cursor[d], 1u);
  uint32_t pos = row_start[d] + off;
  emeta[pos] = make_int2(s << 8, __float_as_int(w));
}

// W1 fp32 [k][f] -> f16 frag-packed: W1P[((k>>3)*128 + f)*8 + (k&7)]
__global__ void k_w1pack(const float* __restrict__ W1, uint16_t* __restrict__ W1P){
  int i = blockIdx.x * 256 + threadIdx.x;
  if (i >= 16 * 128 * 8) return;
  int e = i & 7, f = (i >> 3) & 127, q = i >> 10;
  int k = q * 8 + e;
  W1P[i] = (uint16_t)(pk_f16(W1[k * 128 + f], 0.0f) & 0xffffu);
}

// fp32 -> packed f16: 32B read / 16B write per lane, cvt_pkrtz pack, grid-stride
__global__ void k_cvt(const float4* __restrict__ x, uint4* __restrict__ xb, int n_u4){
  int i = blockIdx.x * 256 + threadIdx.x;
  int stride = gridDim.x * 256;
  for (; i < n_u4; i += stride){
    float4 f0 = x[2 * i];
    float4 f1 = x[2 * i + 1];
    uint4 o;
    o.x = pk_f16(f0.x, f0.y);
    o.y = pk_f16(f0.z, f0.w);
    o.z = pk_f16(f1.x, f1.y);
    o.w = pk_f16(f1.z, f1.w);
    xb[i] = o;
  }
}

// ---------------- fused phase A+B ----------------
// Block = 16-node tile x one batch. 4 waves x 4 nodes each: gather-aggregate
// (same pipeline as before: dwordx4 gathers, 4 edge-groups, 16 edges in flight,
// v_fma_mix consume) -> aggregated f16 rows into LDS tile. One barrier, then each
// wave MFMAs the 16x128 tile against its 32 W1 columns (layouts identical to the
// previously verified k_gemm) and reduces c-weighted ReLU rows into S atomically.
// Eliminates the yb global round-trip (164 MB write + 164 MB read) and a dispatch.
__global__ __launch_bounds__(256) void k_agg(const uint32_t* __restrict__ xb,
                      const int2* __restrict__ emeta, const uint32_t* __restrict__ row_start,
                      const uint32_t* __restrict__ hist, const float* __restrict__ dinv,
                      const uint16_t* __restrict__ W1P, const float* __restrict__ b1,
                      const float* __restrict__ cw, float* __restrict__ S, int b_global0){
  const int wv = threadIdx.x >> 6, lane = threadIdx.x & 63;
  const int g = lane >> 4, s = lane & 15;
  const int n0 = blockIdx.x * 16;                 // 20000 % 16 == 0 -> no tail
  const uint32_t bl = blockIdx.y;
  const char* xbase = (const char*)xb + (size_t)bl * ((size_t)N_NODES * 256);
  const uint32_t s16 = (uint32_t)s * 16u;

  __shared__ uint16_t ylds[16][136];              // 272B row stride: 2-way bank alias (free)

#define CONS(VV, WW) do { \
    fmix_lo(a0, (VV).x, (WW)); fmix_hi(a1, (VV).x, (WW)); \
    fmix_lo(a2, (VV).y, (WW)); fmix_hi(a3, (VV).y, (WW)); \
    fmix_lo(a4, (VV).z, (WW)); fmix_hi(a5, (VV).z, (WW)); \
    fmix_lo(a6, (VV).w, (WW)); fmix_hi(a7, (VV).w, (WW)); \
  } while(0)

#define PREP(P, VV, WW) do { \
    uint32_t idx_ = sbase + (P)*4u + (uint32_t)g; \
    uint32_t ci_  = (idx_ < lim) ? idx_ : (lim - 1u); \
    uint32_t so_  = (uint32_t)__shfl(mx, (int)ci_); \
    float    wf_  = __int_as_float(__shfl(my, (int)ci_)); \
    WW = (idx_ < lim) ? wf_ : 0.0f; \
    VV = *reinterpret_cast<const uint4*>(xbase + (so_ + s16)); \
  } while(0)

  for (int ni = 0; ni < 4; ++ni){
    const int n = n0 + wv * 4 + ni;

    float a0=0.f, a1=0.f, a2=0.f, a3=0.f, a4=0.f, a5=0.f, a6=0.f, a7=0.f;

    // self term: all 4 groups load the same row (HW broadcasts), weight self/4
    float di = dinv[n];
    {
      uint4 sv = *reinterpret_cast<const uint4*>(xbase + ((uint32_t)n * 256u + s16));
      float wself = di * di * 0.25f;
      CONS(sv, wself);
    }

    uint32_t rs  = (uint32_t)__builtin_amdgcn_readfirstlane((int)row_start[n]);
    uint32_t cnt = (uint32_t)__builtin_amdgcn_readfirstlane((int)hist[n]);

    for (uint32_t cbase = 0; cbase < cnt; cbase += 64u){
      uint32_t lim = cnt - cbase; if (lim > 64u) lim = 64u; // edges in this chunk, >=1
      uint32_t cl = (uint32_t)lane; if (cl >= lim) cl = lim - 1u;
      int2 m = emeta[rs + cbase + cl];                      // one coalesced 512B load
      int mx = m.x, my = m.y;

      uint32_t sbase = 0;
      while (sbase + 16u <= lim){                           // full 16-edge super-steps
        uint4 p0, p1, p2, p3; float q0, q1, q2, q3;
        PREP(0, p0, q0); PREP(1, p1, q1); PREP(2, p2, q2); PREP(3, p3, q3);
        CONS(p0, q0); CONS(p1, q1); CONS(p2, q2); CONS(p3, q3);
        sbase += 16u;
      }
      if (sbase < lim){                                     // tail: 1..15 edges
        uint32_t live = lim - sbase;
        uint4 p0, p1, p2, p3; float q0, q1, q2, q3;
        PREP(0, p0, q0);
        if (live > 4u)  { PREP(1, p1, q1); }
        if (live > 8u)  { PREP(2, p2, q2); }
        if (live > 12u) { PREP(3, p3, q3); }
        CONS(p0, q0);
        if (live > 4u)  { CONS(p1, q1); }
        if (live > 8u)  { CONS(p2, q2); }
        if (live > 12u) { CONS(p3, q3); }
      }
    }

    // reduce over the 4 edge-groups: lanes {s, s+16, s+32, s+48} hold same features
    a0 += __shfl_xor(a0, 16); a0 += __shfl_xor(a0, 32);
    a1 += __shfl_xor(a1, 16); a1 += __shfl_xor(a1, 32);
    a2 += __shfl_xor(a2, 16); a2 += __shfl_xor(a2, 32);
    a3 += __shfl_xor(a3, 16); a3 += __shfl_xor(a3, 32);
    a4 += __shfl_xor(a4, 16); a4 += __shfl_xor(a4, 32);
    a5 += __shfl_xor(a5, 16); a5 += __shfl_xor(a5, 32);
    a6 += __shfl_xor(a6, 16); a6 += __shfl_xor(a6, 32);
    a7 += __shfl_xor(a7, 16); a7 += __shfl_xor(a7, 32);

    if (lane < 16){
      uint4 o;
      o.x = pk_f16(a0, a1);
      o.y = pk_f16(a2, a3);
      o.z = pk_f16(a4, a5);
      o.w = pk_f16(a6, a7);
      *reinterpret_cast<uint4*>(&ylds[wv * 4 + ni][s * 8]) = o;   // f16 cols 8s..8s+7
    }
  }
#undef PREP
#undef CONS

  __syncthreads();
  __builtin_amdgcn_sched_barrier(0);              // keep W1 frag loads below the agg loops

  // launder W1P so the scheduler can't hoist 64 VGPRs of frags across the gathers
  uintptr_t w1pp = (uintptr_t)W1P;
  asm volatile("" : "+s"(w1pp));
  const uint16_t* W1Pv = (const uint16_t*)w1pp;

  // A-frags from LDS: lane (q=g, l15=s) reads row l15, elems k = q32*32 + q*8 + e
  v8h av[4];
  #pragma unroll
  for (int q32 = 0; q32 < 4; q32++)
    av[q32] = *reinterpret_cast<const v8h*>(&ylds[s][q32 * 32 + g * 8]);

  // B-frags: this wave covers cols ft = wv*2 + ftl (32 columns)
  v8h bfr[4][2];
  #pragma unroll
  for (int q32 = 0; q32 < 4; q32++)
    #pragma unroll
    for (int ftl = 0; ftl < 2; ftl++)
      bfr[q32][ftl] = *reinterpret_cast<const v8h*>(
          W1Pv + ((q32 * 4 + g) * 128 + (wv * 2 + ftl) * 16 + s) * 8);

  v4f acc[2] = {(v4f){0.f,0.f,0.f,0.f}, (v4f){0.f,0.f,0.f,0.f}};
  #pragma unroll
  for (int q32 = 0; q32 < 4; q32++){
    acc[0] = __builtin_amdgcn_mfma_f32_16x16x32_f16(av[q32], bfr[q32][0], acc[0], 0, 0, 0);
    acc[1] = __builtin_amdgcn_mfma_f32_16x16x32_f16(av[q32], bfr[q32][1], acc[1], 0, 0, 0);
  }

  // epilogue: D row = q*4 + r (local), col = ft*16 + l15; + b1, relu, * cw, reduce
  float b1v[2] = { b1[(wv * 2) * 16 + s], b1[(wv * 2 + 1) * 16 + s] };
  float4 cvv = *reinterpret_cast<const float4*>(cw + n0 + g * 4);
  float cvr[4] = {cvv.x, cvv.y, cvv.z, cvv.w};
  #pragma unroll
  for (int ftl = 0; ftl < 2; ftl++){
    float v = 0.f;
    #pragma unroll
    for (int r = 0; r < 4; r++){
      float h = acc[ftl][r] + b1v[ftl];
      h = fmaxf(h, 0.0f);
      v = fmaf(h, cvr[r], v);
    }
    v += __shfl_xor(v, 16);
    v += __shfl_xor(v, 32);
    if (lane < 16)
      atomicAdd(&S[(b_global0 + (int)bl) * DIM + (wv * 2 + ftl) * 16 + lane], v);
  }
}

// ---------------- final: out[b,f] = (S[b,:]/N)·W2[:,f] + b2[f] ----------------
__global__ void k_final(const float* __restrict__ S, const float* __restrict__ W2,
                        const float* __restrict__ b2, float* __restrict__ out){
  int i = blockIdx.x * 256 + threadIdx.x;
  if (i >= N_BATCH * DIM) return;
  int b = i >> 7, f = i & 127;
  float o = 0.0f;
  const float invN = 1.0f / (float)N_NODES;
  #pragma unroll 4
  for (int k = 0; k < 128; k++)
    o = fmaf(S[b * 128 + k], W2[k * 128 + f], o);
  out[i] = fmaf(o, invN, b2[f]);
}

// ---------------- host ----------------

extern "C" void kernel_launch(void* const* d_in, const int* in_sizes, int n_in,
                              void* d_out, int out_size, void* d_ws, size_t ws_size,
                              hipStream_t stream){
  const float* gene = (const float*)d_in[0];
  const int*   ei   = (const int*)d_in[1];
  const float* W1   = (const float*)d_in[2];
  const float* b1   = (const float*)d_in[3];
  const float* W2   = (const float*)d_in[4];
  const float* b2   = (const float*)d_in[5];
  float* out = (float*)d_out;

  char* base = (char*)d_ws;
  size_t off = 0;
  auto take = [&](size_t bytes)->char*{
    char* p = base + off;
    off = (off + bytes + 255) & ~(size_t)255;
    return p;
  };

  // zero zone: hist (N+1) | cursor (N) | S (B*128 f32)  -- one contiguous zero pass
  const int ZWORDS = (N_NODES + 1) + N_NODES + N_BATCH * DIM;
  uint32_t* zzone  = (uint32_t*)take((size_t)ZWORDS * 4);
  uint32_t* hist   = zzone;
  uint32_t* cursor = zzone + (N_NODES + 1);
  float*    S      = (float*)(zzone + (N_NODES + 1) + N_NODES);

  uint32_t* row_start = (uint32_t*)take((size_t)N_NODES * 4);
  float*    dinv      = (float*)take((size_t)N_NODES * 4);
  float*    cw        = (float*)take((size_t)N_NODES * 4);
  int2*     emeta     = (int2*)take((size_t)N_EDGES * 8);
  uint16_t* W1P       = (uint16_t*)take((size_t)16 * 128 * 8 * 2);

  // batch-chunked x f16 slab (yb eliminated by fusion)
  const size_t per_batch = (size_t)N_NODES * DIM * 2;   // 5.12 MB
  size_t remain = (ws_size > off) ? (ws_size - off) : 0;
  int C = (int)(remain / per_batch);
  if (C < 1) C = 1;
  if (C > N_BATCH) C = N_BATCH;
  uint32_t* xb = (uint32_t*)take(per_batch * C);

  k_zero<<<cdiv(ZWORDS, 256), 256, 0, stream>>>(zzone, ZWORDS);
  k_hist<<<cdiv(N_EDGES, 256), 256, 0, stream>>>(ei, hist);
  k_scan<<<1, 1024, 0, stream>>>(hist, row_start, dinv, cw);
  k_edge<<<cdiv(N_EDGES, 256), 256, 0, stream>>>(ei, row_start, cursor, dinv, cw, emeta);
  k_w1pack<<<64, 256, 0, stream>>>(W1, W1P);

  for (int b0 = 0; b0 < N_BATCH; b0 += C){
    int Cb = (N_BATCH - b0 < C) ? (N_BATCH - b0) : C;
    int nu4 = Cb * N_NODES * (DIM / 8);
    int cvtb = cdiv(nu4, 256 * 8); if (cvtb > 2048) cvtb = 2048;
    k_cvt<<<cvtb, 256, 0, stream>>>(((const float4*)gene) + (size_t)b0 * N_NODES * (DIM / 4),
                                    (uint4*)xb, nu4);
    k_agg<<<dim3(N_NODES / 16, Cb), 256, 0, stream>>>(xb, emeta, row_start, hist, dinv,
                                                      W1P, b1, cw, S, b0);
  }

  k_final<<<cdiv(N_BATCH * DIM, 256), 256, 0, stream>>>(S, W2, b2, out);
}